// Round 14
// baseline (410.263 us; speedup 1.0000x reference)
//
#include <hip/hip_runtime.h>

// MMoE: B=16384 D=512 U=128 E=16 T=4, fp32 in/out.
// vs round-12 (PASSING, 100.7us; r13 gload_lds regressed -> reverted):
//  moe changes only: (1) LDS pads -> T2 XOR swizzle (both write+read side,
//  reg-staged), staging 55.3->48KB; (2) two-pass epilogue with [64][264]
//  eo-half overlay (33.8KB). LDS 67.6->48KB => 3 blocks/CU.
//  Same bf16 values at all rounding points; same contraction order.
// gates/convert_ek/XCD-swizzle/T14-prefetch: r12 VERBATIM.
// ws: gates 4MiB @0, xb 16MiB @4MiB, ekT 2MiB @20MiB.

#define Bsz 16384
#define Dd  512
#define Uu  128
#define Ee  16
#define Tt  4
#define Nn  2048   // U*E

typedef short bf16x8 __attribute__((ext_vector_type(8)));
typedef float f32x4 __attribute__((ext_vector_type(4)));
typedef unsigned short u16x8 __attribute__((ext_vector_type(8)));

static __device__ __forceinline__ unsigned short f2bf(float f) {
    unsigned int u = __builtin_bit_cast(unsigned int, f);
    u += 0x7fffu + ((u >> 16) & 1u);   // round-to-nearest-even
    return (unsigned short)(u >> 16);
}
static __device__ __forceinline__ float bf2f(unsigned short s) {
    return __builtin_bit_cast(float, (unsigned int)s << 16);
}

// ---------------- Kernel 0: ek -> ekT bf16 transpose (r10-12 verbatim) ----------------
__global__ __launch_bounds__(256) void convert_ek(
        const float* __restrict__ ek, unsigned short* __restrict__ ekT) {
    __shared__ unsigned short ts[64 * 65];
    const int bx = blockIdx.x, tid = threadIdx.x;
    const int n0 = (bx & 31) * 64, d0 = (bx >> 5) * 64;
    #pragma unroll
    for (int i = 0; i < 4; ++i) {
        int flat = i * 256 + tid;
        int dl = flat >> 4, ng = (flat & 15) * 4;
        const float4 v = *(const float4*)(ek + (size_t)(d0 + dl) * Nn + n0 + ng);
        ts[(ng + 0) * 65 + dl] = f2bf(v.x);
        ts[(ng + 1) * 65 + dl] = f2bf(v.y);
        ts[(ng + 2) * 65 + dl] = f2bf(v.z);
        ts[(ng + 3) * 65 + dl] = f2bf(v.w);
    }
    __syncthreads();
    #pragma unroll
    for (int i = 0; i < 4; ++i) {
        int flat = i * 256 + tid;
        int nl = flat >> 4, dg = (flat & 15) * 4;
        ushort4 w = make_ushort4(ts[nl * 65 + dg], ts[nl * 65 + dg + 1],
                                 ts[nl * 65 + dg + 2], ts[nl * 65 + dg + 3]);
        *(ushort4*)(ekT + (size_t)(n0 + nl) * Dd + d0 + dg) = w;
    }
}

// ---------------- Kernel 1: gates + fused x->bf16 conversion (r12 verbatim) ----------------
__global__ __launch_bounds__(256) void gates_kernel(
        const float* __restrict__ x, const float* __restrict__ gk,
        const float* __restrict__ gb, float* __restrict__ gates,
        unsigned short* __restrict__ xb) {
    __shared__ __align__(16) float xl[16][128];    // 8 KB
    __shared__ __align__(16) float gkl[128][64];   // 32 KB
    const int tid = threadIdx.x;
    const int w = tid >> 6, lane = tid & 63;
    const int b0 = blockIdx.x * 16;
    float acc[4] = {0.f, 0.f, 0.f, 0.f};

    for (int c = 0; c < 4; ++c) {
        const int d0 = c * 128;
        __syncthreads();  // previous chunk consumed
        #pragma unroll
        for (int p = 0; p < 2; ++p) {
            const int flat = p * 256 + tid;
            const int row = flat >> 5, c4 = (flat & 31) * 4;
            const float4 v =
                *(const float4*)(x + (size_t)(b0 + row) * Dd + d0 + c4);
            *(float4*)(&xl[row][c4]) = v;
            *(ushort4*)(xb + (size_t)(b0 + row) * Dd + d0 + c4) =
                make_ushort4(f2bf(v.x), f2bf(v.y), f2bf(v.z), f2bf(v.w));
        }
        {
            const int n = tid & 63, dl0 = tid >> 6;
            const float* gp = gk + (size_t)(n >> 4) * (Dd * Ee) + (n & 15)
                                 + (size_t)(d0 + dl0) * Ee;
            #pragma unroll
            for (int j = 0; j < 32; ++j)
                gkl[dl0 + j * 4][n] = gp[(size_t)j * 4 * Ee];
        }
        __syncthreads();
        #pragma unroll 4
        for (int dq = 0; dq < 32; ++dq) {
            float wv[4];
            #pragma unroll
            for (int q = 0; q < 4; ++q) wv[q] = gkl[dq * 4 + q][lane];
            #pragma unroll
            for (int r = 0; r < 4; ++r) {
                const float4 xv = *(const float4*)(&xl[w * 4 + r][dq * 4]);
                float a = acc[r];
                a = fmaf(xv.x, wv[0], a);
                a = fmaf(xv.y, wv[1], a);
                a = fmaf(xv.z, wv[2], a);
                a = fmaf(xv.w, wv[3], a);
                acc[r] = a;
            }
        }
    }
    const float bias = gb[lane];
    #pragma unroll
    for (int r = 0; r < 4; ++r) {
        float a = acc[r] + bias;
        float m = a;
        m = fmaxf(m, __shfl_xor(m, 1));
        m = fmaxf(m, __shfl_xor(m, 2));
        m = fmaxf(m, __shfl_xor(m, 4));
        m = fmaxf(m, __shfl_xor(m, 8));
        float p = __expf(a - m);
        float s = p;
        s += __shfl_xor(s, 1);
        s += __shfl_xor(s, 2);
        s += __shfl_xor(s, 4);
        s += __shfl_xor(s, 8);
        gates[(size_t)(b0 + w * 4 + r) * 64 + lane] = p / s;  // [b][t*16+e]
    }
}

// ---------------- Kernel 2: expert GEMM + relu + gate contraction ----------------
// r12 loop structure; XOR-swizzled unpadded tiles; two-pass epilogue.
#define BM 128
#define BN 256   // = 16 u's x 16 e's (n = u*16+e)
#define BK 64

__global__ __launch_bounds__(512, 6) void moe_kernel(
        const unsigned short* __restrict__ xb,
        const unsigned short* __restrict__ ekT,
        const float* __restrict__ eb, const float* __restrict__ gates,
        float* __restrict__ out) {
    __shared__ __align__(16) unsigned short smem[24576];  // 49152 B
    char* sAb = (char*)smem;            // A tile: 128 rows x 128 B, swizzled
    char* sBb = (char*)smem + 16384;    // B tile: 256 rows x 128 B, swizzled

    const int tid = threadIdx.x;
    const int wave = tid >> 6, lane = tid & 63;
    const int llo = lane & 15, lhi = lane >> 4;
    // XCD swizzle (r12 verbatim): bijective for 1024 blocks.
    const int g = (blockIdx.x & 7) * 128 + (blockIdx.x >> 3);
    const int b0 = (g >> 3) * BM;
    const int n0 = (g & 7) * BN;
    const int mr = (wave >> 2) * 64;  // wave row origin
    const int nc = (wave & 3) * 64;   // wave col origin

    f32x4 acc[4][4] = {};
    u16x8 va[2], vb[4];

    // prologue: load tile kt=0 into regs (r12 verbatim)
    #pragma unroll
    for (int i = 0; i < 2; ++i) {
        int f = i * 512 + tid;
        va[i] = *(const u16x8*)(xb + (size_t)(b0 + (f >> 3)) * Dd + (f & 7) * 8);
    }
    #pragma unroll
    for (int i = 0; i < 4; ++i) {
        int f = i * 512 + tid;
        vb[i] = *(const u16x8*)(ekT + (size_t)(n0 + (f >> 3)) * Dd + (f & 7) * 8);
    }

    for (int kt = 0; kt < Dd / BK; ++kt) {
        __syncthreads();  // previous tile's MFMA reads done
        // ds_write current tile, XOR-swizzled: chunk c of row r -> slot c^(r&7)
        #pragma unroll
        for (int i = 0; i < 2; ++i) {
            int f = i * 512 + tid;
            int row = f >> 3, c = f & 7;
            *(u16x8*)(sAb + row * 128 + ((c ^ (row & 7)) << 4)) = va[i];
        }
        #pragma unroll
        for (int i = 0; i < 4; ++i) {
            int f = i * 512 + tid;
            int row = f >> 3, c = f & 7;
            *(u16x8*)(sBb + row * 128 + ((c ^ (row & 7)) << 4)) = vb[i];
        }
        // T14: issue next tile's global loads (r12 verbatim)
        if (kt < Dd / BK - 1) {
            const int k1 = (kt + 1) * BK;
            #pragma unroll
            for (int i = 0; i < 2; ++i) {
                int f = i * 512 + tid;
                va[i] = *(const u16x8*)(xb + (size_t)(b0 + (f >> 3)) * Dd + k1 + (f & 7) * 8);
            }
            #pragma unroll
            for (int i = 0; i < 4; ++i) {
                int f = i * 512 + tid;
                vb[i] = *(const u16x8*)(ekT + (size_t)(n0 + (f >> 3)) * Dd + k1 + (f & 7) * 8);
            }
        }
        __syncthreads();
        #pragma unroll
        for (int ks = 0; ks < BK; ks += 32) {
            bf16x8 aF[4], bF[4];
            const int sl = (ks >> 3) + lhi;          // logical 16B slot
            const int ph = (sl ^ (llo & 7)) << 4;    // row&7 == llo&7 for reads
            #pragma unroll
            for (int mi = 0; mi < 4; ++mi)
                aF[mi] = *(const bf16x8*)(sAb + (mr + mi * 16 + llo) * 128 + ph);
            #pragma unroll
            for (int ni = 0; ni < 4; ++ni)
                bF[ni] = *(const bf16x8*)(sBb + (nc + ni * 16 + llo) * 128 + ph);
            #pragma unroll
            for (int mi = 0; mi < 4; ++mi)
                #pragma unroll
                for (int ni = 0; ni < 4; ++ni)
                    acc[mi][ni] = __builtin_amdgcn_mfma_f32_16x16x32_bf16(
                        aF[mi], bF[ni], acc[mi][ni], 0, 0, 0);
        }
    }

    // -------- two-pass epilogue: eo half-tile [64][264] overlays staging --------
    unsigned short* eoh = smem;
    #pragma unroll
    for (int pass = 0; pass < 2; ++pass) {
        __syncthreads();  // staging reads (pass 0) / prev contraction (pass 1) done
        if ((mr >> 6) == pass) {  // waves owning rows pass*64..+63 write
            #pragma unroll
            for (int ni = 0; ni < 4; ++ni) {
                const int col = nc + ni * 16 + llo;
                const float ebv = eb[n0 + col];
                #pragma unroll
                for (int mi = 0; mi < 4; ++mi)
                    #pragma unroll
                    for (int j = 0; j < 4; ++j) {
                        int rl = mi * 16 + lhi * 4 + j;  // local row 0..63
                        eoh[rl * 264 + col] = f2bf(fmaxf(acc[mi][ni][j] + ebv, 0.f));
                    }
            }
        }
        __syncthreads();
        // contraction for rows pass*64..+63: 1024 tasks over 512 threads
        #pragma unroll
        for (int i = 0; i < 2; ++i) {
            int f = i * 512 + tid;
            int ml = f >> 4, ul = f & 15;
            const unsigned short* er = eoh + ml * 264 + ul * 16;
            const int brow = b0 + pass * 64 + ml;
            const float* gr = gates + (size_t)brow * 64;
            float o0 = 0.f, o1 = 0.f, o2 = 0.f, o3 = 0.f;
            #pragma unroll
            for (int e = 0; e < 16; ++e) {
                float v = bf2f(er[e]);
                o0 = fmaf(v, gr[e], o0);
                o1 = fmaf(v, gr[16 + e], o1);
                o2 = fmaf(v, gr[32 + e], o2);
                o3 = fmaf(v, gr[48 + e], o3);
            }
            size_t base = (size_t)brow * Uu + (n0 >> 4) + ul;
            out[base] = o0;
            out[(size_t)Bsz * Uu + base] = o1;
            out[2 * (size_t)Bsz * Uu + base] = o2;
            out[3 * (size_t)Bsz * Uu + base] = o3;
        }
    }
}

extern "C" void kernel_launch(void* const* d_in, const int* in_sizes, int n_in,
                              void* d_out, int out_size, void* d_ws, size_t ws_size,
                              hipStream_t stream) {
    const float* x  = (const float*)d_in[0];
    const float* ek = (const float*)d_in[1];
    const float* eb = (const float*)d_in[2];
    const float* gk = (const float*)d_in[3];
    const float* gb = (const float*)d_in[4];
    float* out = (float*)d_out;

    char* wsb = (char*)d_ws;
    float* gates       = (float*)wsb;                            // 4 MiB @ 0
    unsigned short* xb  = (unsigned short*)(wsb + (4u << 20));   // 16 MiB @ 4
    unsigned short* ekT = (unsigned short*)(wsb + (20u << 20));  // 2 MiB @ 20

    gates_kernel<<<Bsz / 16, 256, 0, stream>>>(x, gk, gb, gates, xb);
    convert_ek<<<256, 256, 0, stream>>>(ek, ekT);
    moe_kernel<<<1024, 512, 0, stream>>>(xb, ekT, eb, gates, out);
}

// Round 16
// 103.276 us; speedup vs baseline: 3.9725x; 3.9725x over previous
//
#include <hip/hip_runtime.h>

// MMoE: B=16384 D=512 U=128 E=16 T=4, fp32 in/out.
// vs round-14 (PASSED but 5.7x regression from acc spill): ONE change —
// __launch_bounds__(512,6) -> __launch_bounds__(512). r14's min-waves=6
// clause capped VGPRs (76->40) and spilled acc to scratch (FETCH 583MB).
// Keep r14's verified wins: T2 XOR swizzle (bank conflicts -> 0), 49152B
// LDS (3 blocks/CU), two-pass epilogue. All values bit-identical.
// gates/convert_ek/XCD-swizzle/T14-prefetch: r12 VERBATIM.
// [Round 16 = round 15 resubmitted verbatim: r15 bench died on
//  UnresponsiveContainer (infra) before measuring anything.]
// ws: gates 4MiB @0, xb 16MiB @4MiB, ekT 2MiB @20MiB.

#define Bsz 16384
#define Dd  512
#define Uu  128
#define Ee  16
#define Tt  4
#define Nn  2048   // U*E

typedef short bf16x8 __attribute__((ext_vector_type(8)));
typedef float f32x4 __attribute__((ext_vector_type(4)));
typedef unsigned short u16x8 __attribute__((ext_vector_type(8)));

static __device__ __forceinline__ unsigned short f2bf(float f) {
    unsigned int u = __builtin_bit_cast(unsigned int, f);
    u += 0x7fffu + ((u >> 16) & 1u);   // round-to-nearest-even
    return (unsigned short)(u >> 16);
}
static __device__ __forceinline__ float bf2f(unsigned short s) {
    return __builtin_bit_cast(float, (unsigned int)s << 16);
}

// ---------------- Kernel 0: ek -> ekT bf16 transpose (r10-12 verbatim) ----------------
__global__ __launch_bounds__(256) void convert_ek(
        const float* __restrict__ ek, unsigned short* __restrict__ ekT) {
    __shared__ unsigned short ts[64 * 65];
    const int bx = blockIdx.x, tid = threadIdx.x;
    const int n0 = (bx & 31) * 64, d0 = (bx >> 5) * 64;
    #pragma unroll
    for (int i = 0; i < 4; ++i) {
        int flat = i * 256 + tid;
        int dl = flat >> 4, ng = (flat & 15) * 4;
        const float4 v = *(const float4*)(ek + (size_t)(d0 + dl) * Nn + n0 + ng);
        ts[(ng + 0) * 65 + dl] = f2bf(v.x);
        ts[(ng + 1) * 65 + dl] = f2bf(v.y);
        ts[(ng + 2) * 65 + dl] = f2bf(v.z);
        ts[(ng + 3) * 65 + dl] = f2bf(v.w);
    }
    __syncthreads();
    #pragma unroll
    for (int i = 0; i < 4; ++i) {
        int flat = i * 256 + tid;
        int nl = flat >> 4, dg = (flat & 15) * 4;
        ushort4 w = make_ushort4(ts[nl * 65 + dg], ts[nl * 65 + dg + 1],
                                 ts[nl * 65 + dg + 2], ts[nl * 65 + dg + 3]);
        *(ushort4*)(ekT + (size_t)(n0 + nl) * Dd + d0 + dg) = w;
    }
}

// ---------------- Kernel 1: gates + fused x->bf16 conversion (r12 verbatim) ----------------
__global__ __launch_bounds__(256) void gates_kernel(
        const float* __restrict__ x, const float* __restrict__ gk,
        const float* __restrict__ gb, float* __restrict__ gates,
        unsigned short* __restrict__ xb) {
    __shared__ __align__(16) float xl[16][128];    // 8 KB
    __shared__ __align__(16) float gkl[128][64];   // 32 KB
    const int tid = threadIdx.x;
    const int w = tid >> 6, lane = tid & 63;
    const int b0 = blockIdx.x * 16;
    float acc[4] = {0.f, 0.f, 0.f, 0.f};

    for (int c = 0; c < 4; ++c) {
        const int d0 = c * 128;
        __syncthreads();  // previous chunk consumed
        #pragma unroll
        for (int p = 0; p < 2; ++p) {
            const int flat = p * 256 + tid;
            const int row = flat >> 5, c4 = (flat & 31) * 4;
            const float4 v =
                *(const float4*)(x + (size_t)(b0 + row) * Dd + d0 + c4);
            *(float4*)(&xl[row][c4]) = v;
            *(ushort4*)(xb + (size_t)(b0 + row) * Dd + d0 + c4) =
                make_ushort4(f2bf(v.x), f2bf(v.y), f2bf(v.z), f2bf(v.w));
        }
        {
            const int n = tid & 63, dl0 = tid >> 6;
            const float* gp = gk + (size_t)(n >> 4) * (Dd * Ee) + (n & 15)
                                 + (size_t)(d0 + dl0) * Ee;
            #pragma unroll
            for (int j = 0; j < 32; ++j)
                gkl[dl0 + j * 4][n] = gp[(size_t)j * 4 * Ee];
        }
        __syncthreads();
        #pragma unroll 4
        for (int dq = 0; dq < 32; ++dq) {
            float wv[4];
            #pragma unroll
            for (int q = 0; q < 4; ++q) wv[q] = gkl[dq * 4 + q][lane];
            #pragma unroll
            for (int r = 0; r < 4; ++r) {
                const float4 xv = *(const float4*)(&xl[w * 4 + r][dq * 4]);
                float a = acc[r];
                a = fmaf(xv.x, wv[0], a);
                a = fmaf(xv.y, wv[1], a);
                a = fmaf(xv.z, wv[2], a);
                a = fmaf(xv.w, wv[3], a);
                acc[r] = a;
            }
        }
    }
    const float bias = gb[lane];
    #pragma unroll
    for (int r = 0; r < 4; ++r) {
        float a = acc[r] + bias;
        float m = a;
        m = fmaxf(m, __shfl_xor(m, 1));
        m = fmaxf(m, __shfl_xor(m, 2));
        m = fmaxf(m, __shfl_xor(m, 4));
        m = fmaxf(m, __shfl_xor(m, 8));
        float p = __expf(a - m);
        float s = p;
        s += __shfl_xor(s, 1);
        s += __shfl_xor(s, 2);
        s += __shfl_xor(s, 4);
        s += __shfl_xor(s, 8);
        gates[(size_t)(b0 + w * 4 + r) * 64 + lane] = p / s;  // [b][t*16+e]
    }
}

// ---------------- Kernel 2: expert GEMM + relu + gate contraction ----------------
// r14 structure; plain launch_bounds (no min-waves VGPR cap).
#define BM 128
#define BN 256   // = 16 u's x 16 e's (n = u*16+e)
#define BK 64

__global__ __launch_bounds__(512) void moe_kernel(
        const unsigned short* __restrict__ xb,
        const unsigned short* __restrict__ ekT,
        const float* __restrict__ eb, const float* __restrict__ gates,
        float* __restrict__ out) {
    __shared__ __align__(16) unsigned short smem[24576];  // 49152 B
    char* sAb = (char*)smem;            // A tile: 128 rows x 128 B, swizzled
    char* sBb = (char*)smem + 16384;    // B tile: 256 rows x 128 B, swizzled

    const int tid = threadIdx.x;
    const int wave = tid >> 6, lane = tid & 63;
    const int llo = lane & 15, lhi = lane >> 4;
    // XCD swizzle (r12 verbatim): bijective for 1024 blocks.
    const int g = (blockIdx.x & 7) * 128 + (blockIdx.x >> 3);
    const int b0 = (g >> 3) * BM;
    const int n0 = (g & 7) * BN;
    const int mr = (wave >> 2) * 64;  // wave row origin
    const int nc = (wave & 3) * 64;   // wave col origin

    f32x4 acc[4][4] = {};
    u16x8 va[2], vb[4];

    // prologue: load tile kt=0 into regs (r12 verbatim)
    #pragma unroll
    for (int i = 0; i < 2; ++i) {
        int f = i * 512 + tid;
        va[i] = *(const u16x8*)(xb + (size_t)(b0 + (f >> 3)) * Dd + (f & 7) * 8);
    }
    #pragma unroll
    for (int i = 0; i < 4; ++i) {
        int f = i * 512 + tid;
        vb[i] = *(const u16x8*)(ekT + (size_t)(n0 + (f >> 3)) * Dd + (f & 7) * 8);
    }

    for (int kt = 0; kt < Dd / BK; ++kt) {
        __syncthreads();  // previous tile's MFMA reads done
        // ds_write current tile, XOR-swizzled: chunk c of row r -> slot c^(r&7)
        #pragma unroll
        for (int i = 0; i < 2; ++i) {
            int f = i * 512 + tid;
            int row = f >> 3, c = f & 7;
            *(u16x8*)(sAb + row * 128 + ((c ^ (row & 7)) << 4)) = va[i];
        }
        #pragma unroll
        for (int i = 0; i < 4; ++i) {
            int f = i * 512 + tid;
            int row = f >> 3, c = f & 7;
            *(u16x8*)(sBb + row * 128 + ((c ^ (row & 7)) << 4)) = vb[i];
        }
        // T14: issue next tile's global loads (r12 verbatim)
        if (kt < Dd / BK - 1) {
            const int k1 = (kt + 1) * BK;
            #pragma unroll
            for (int i = 0; i < 2; ++i) {
                int f = i * 512 + tid;
                va[i] = *(const u16x8*)(xb + (size_t)(b0 + (f >> 3)) * Dd + k1 + (f & 7) * 8);
            }
            #pragma unroll
            for (int i = 0; i < 4; ++i) {
                int f = i * 512 + tid;
                vb[i] = *(const u16x8*)(ekT + (size_t)(n0 + (f >> 3)) * Dd + k1 + (f & 7) * 8);
            }
        }
        __syncthreads();
        #pragma unroll
        for (int ks = 0; ks < BK; ks += 32) {
            bf16x8 aF[4], bF[4];
            const int sl = (ks >> 3) + lhi;          // logical 16B slot
            const int ph = (sl ^ (llo & 7)) << 4;    // row&7 == llo&7 for reads
            #pragma unroll
            for (int mi = 0; mi < 4; ++mi)
                aF[mi] = *(const bf16x8*)(sAb + (mr + mi * 16 + llo) * 128 + ph);
            #pragma unroll
            for (int ni = 0; ni < 4; ++ni)
                bF[ni] = *(const bf16x8*)(sBb + (nc + ni * 16 + llo) * 128 + ph);
            #pragma unroll
            for (int mi = 0; mi < 4; ++mi)
                #pragma unroll
                for (int ni = 0; ni < 4; ++ni)
                    acc[mi][ni] = __builtin_amdgcn_mfma_f32_16x16x32_bf16(
                        aF[mi], bF[ni], acc[mi][ni], 0, 0, 0);
        }
    }

    // -------- two-pass epilogue: eo half-tile [64][264] overlays staging --------
    unsigned short* eoh = smem;
    #pragma unroll
    for (int pass = 0; pass < 2; ++pass) {
        __syncthreads();  // staging reads (pass 0) / prev contraction (pass 1) done
        if ((mr >> 6) == pass) {  // waves owning rows pass*64..+63 write
            #pragma unroll
            for (int ni = 0; ni < 4; ++ni) {
                const int col = nc + ni * 16 + llo;
                const float ebv = eb[n0 + col];
                #pragma unroll
                for (int mi = 0; mi < 4; ++mi)
                    #pragma unroll
                    for (int j = 0; j < 4; ++j) {
                        int rl = mi * 16 + lhi * 4 + j;  // local row 0..63
                        eoh[rl * 264 + col] = f2bf(fmaxf(acc[mi][ni][j] + ebv, 0.f));
                    }
            }
        }
        __syncthreads();
        // contraction for rows pass*64..+63: 1024 tasks over 512 threads
        #pragma unroll
        for (int i = 0; i < 2; ++i) {
            int f = i * 512 + tid;
            int ml = f >> 4, ul = f & 15;
            const unsigned short* er = eoh + ml * 264 + ul * 16;
            const int brow = b0 + pass * 64 + ml;
            const float* gr = gates + (size_t)brow * 64;
            float o0 = 0.f, o1 = 0.f, o2 = 0.f, o3 = 0.f;
            #pragma unroll
            for (int e = 0; e < 16; ++e) {
                float v = bf2f(er[e]);
                o0 = fmaf(v, gr[e], o0);
                o1 = fmaf(v, gr[16 + e], o1);
                o2 = fmaf(v, gr[32 + e], o2);
                o3 = fmaf(v, gr[48 + e], o3);
            }
            size_t base = (size_t)brow * Uu + (n0 >> 4) + ul;
            out[base] = o0;
            out[(size_t)Bsz * Uu + base] = o1;
            out[2 * (size_t)Bsz * Uu + base] = o2;
            out[3 * (size_t)Bsz * Uu + base] = o3;
        }
    }
}

extern "C" void kernel_launch(void* const* d_in, const int* in_sizes, int n_in,
                              void* d_out, int out_size, void* d_ws, size_t ws_size,
                              hipStream_t stream) {
    const float* x  = (const float*)d_in[0];
    const float* ek = (const float*)d_in[1];
    const float* eb = (const float*)d_in[2];
    const float* gk = (const float*)d_in[3];
    const float* gb = (const float*)d_in[4];
    float* out = (float*)d_out;

    char* wsb = (char*)d_ws;
    float* gates       = (float*)wsb;                            // 4 MiB @ 0
    unsigned short* xb  = (unsigned short*)(wsb + (4u << 20));   // 16 MiB @ 4
    unsigned short* ekT = (unsigned short*)(wsb + (20u << 20));  // 2 MiB @ 20

    gates_kernel<<<Bsz / 16, 256, 0, stream>>>(x, gk, gb, gates, xb);
    convert_ek<<<256, 256, 0, stream>>>(ek, ekT);
    moe_kernel<<<1024, 512, 0, stream>>>(xb, ekT, eb, gates, out);
}

// Round 17
// 100.919 us; speedup vs baseline: 4.0653x; 1.0234x over previous
//
#include <hip/hip_runtime.h>

// MMoE: B=16384 D=512 U=128 E=16 T=4, fp32 in/out.
// vs r12/r16: moe rebuilt as counted-vmcnt double-buffered pipeline (T3/T4):
//   global_load_lds staging (linear dest) + pre-swizzled GLOBAL chunk layout
//   (rule #21) + r16's proven swizzled reads; s_waitcnt vmcnt(6) in-loop
//   (never 0), raw s_barrier fused into single asm with "memory" clobber.
//   LDS 96KB dbuf; eo two-pass epilogue (r16-verbatim values).
// prep_kernel = gates(+fused x->xb swz bf16) U convert_ek (one dispatch).
// All computed values bit-identical to r16 (PASSING). ws: gates 4MiB @0,
// xb 16MiB @4MiB, ekT 2MiB @20MiB.

#define Bsz 16384
#define Dd  512
#define Uu  128
#define Ee  16
#define Tt  4
#define Nn  2048   // U*E

typedef short bf16x8 __attribute__((ext_vector_type(8)));
typedef float f32x4 __attribute__((ext_vector_type(4)));
typedef unsigned short u16x8 __attribute__((ext_vector_type(8)));

static __device__ __forceinline__ unsigned short f2bf(float f) {
    unsigned int u = __builtin_bit_cast(unsigned int, f);
    u += 0x7fffu + ((u >> 16) & 1u);   // round-to-nearest-even
    return (unsigned short)(u >> 16);
}
static __device__ __forceinline__ float bf2f(unsigned short s) {
    return __builtin_bit_cast(float, (unsigned int)s << 16);
}

#define GLOAD16(g, l) __builtin_amdgcn_global_load_lds( \
    (const __attribute__((address_space(1))) void*)(g), \
    (__attribute__((address_space(3))) void*)(l), 16, 0, 0)

// swizzled element offset within a row: 16B chunk c of each 64-elem K-tile
// stored at physical chunk c^(row&7). Inverse of the LDS read swizzle.
static __device__ __forceinline__ int swzE(int E, int row) {
    return (E & ~63) | ((((E >> 3) & 7) ^ (row & 7)) << 3) | (E & 7);
}

// ---------------- Kernel A: prep = gates (+x->xb) U convert_ek ----------------
// blocks [0,1024): r12 gates verbatim, xb written chunk-swizzled.
// blocks [1024,1280): r12 convert_ek verbatim, ekT written chunk-swizzled.
__global__ __launch_bounds__(256) void prep_kernel(
        const float* __restrict__ x, const float* __restrict__ gk,
        const float* __restrict__ gb, const float* __restrict__ ek,
        float* __restrict__ gates, unsigned short* __restrict__ xb,
        unsigned short* __restrict__ ekT) {
    __shared__ __align__(16) char pm[40960];
    const int tid = threadIdx.x;
    if (blockIdx.x >= 1024) {
        unsigned short* ts = (unsigned short*)pm;  // [64*65]
        const int b2 = blockIdx.x - 1024;
        const int n0 = (b2 & 31) * 64, d0 = (b2 >> 5) * 64;
        #pragma unroll
        for (int i = 0; i < 4; ++i) {
            int flat = i * 256 + tid;
            int dl = flat >> 4, ng = (flat & 15) * 4;
            const float4 v = *(const float4*)(ek + (size_t)(d0 + dl) * Nn + n0 + ng);
            ts[(ng + 0) * 65 + dl] = f2bf(v.x);
            ts[(ng + 1) * 65 + dl] = f2bf(v.y);
            ts[(ng + 2) * 65 + dl] = f2bf(v.z);
            ts[(ng + 3) * 65 + dl] = f2bf(v.w);
        }
        __syncthreads();
        #pragma unroll
        for (int i = 0; i < 4; ++i) {
            int flat = i * 256 + tid;
            int nl = flat >> 4, dg = (flat & 15) * 4;
            ushort4 w = make_ushort4(ts[nl * 65 + dg], ts[nl * 65 + dg + 1],
                                     ts[nl * 65 + dg + 2], ts[nl * 65 + dg + 3]);
            const int Es = swzE(d0 + dg, nl);  // (n0+nl)&7 == nl&7
            *(ushort4*)(ekT + (size_t)(n0 + nl) * Dd + Es) = w;
        }
        return;
    }
    float (*xl)[128] = (float (*)[128])pm;          // 8 KB
    float (*gkl)[64] = (float (*)[64])(pm + 8192);  // 32 KB
    const int w = tid >> 6, lane = tid & 63;
    const int b0 = blockIdx.x * 16;
    float acc[4] = {0.f, 0.f, 0.f, 0.f};

    for (int c = 0; c < 4; ++c) {
        const int d0 = c * 128;
        __syncthreads();  // previous chunk consumed
        #pragma unroll
        for (int p = 0; p < 2; ++p) {
            const int flat = p * 256 + tid;
            const int row = flat >> 5, c4 = (flat & 31) * 4;
            const float4 v =
                *(const float4*)(x + (size_t)(b0 + row) * Dd + d0 + c4);
            *(float4*)(&xl[row][c4]) = v;
            const int Es = swzE(d0 + c4, row);  // (b0+row)&7 == row&7
            *(ushort4*)(xb + (size_t)(b0 + row) * Dd + Es) =
                make_ushort4(f2bf(v.x), f2bf(v.y), f2bf(v.z), f2bf(v.w));
        }
        {
            const int n = tid & 63, dl0 = tid >> 6;
            const float* gp = gk + (size_t)(n >> 4) * (Dd * Ee) + (n & 15)
                                 + (size_t)(d0 + dl0) * Ee;
            #pragma unroll
            for (int j = 0; j < 32; ++j)
                gkl[dl0 + j * 4][n] = gp[(size_t)j * 4 * Ee];
        }
        __syncthreads();
        #pragma unroll 4
        for (int dq = 0; dq < 32; ++dq) {
            float wv[4];
            #pragma unroll
            for (int q = 0; q < 4; ++q) wv[q] = gkl[dq * 4 + q][lane];
            #pragma unroll
            for (int r = 0; r < 4; ++r) {
                const float4 xv = *(const float4*)(&xl[w * 4 + r][dq * 4]);
                float a = acc[r];
                a = fmaf(xv.x, wv[0], a);
                a = fmaf(xv.y, wv[1], a);
                a = fmaf(xv.z, wv[2], a);
                a = fmaf(xv.w, wv[3], a);
                acc[r] = a;
            }
        }
    }
    const float bias = gb[lane];
    #pragma unroll
    for (int r = 0; r < 4; ++r) {
        float a = acc[r] + bias;
        float m = a;
        m = fmaxf(m, __shfl_xor(m, 1));
        m = fmaxf(m, __shfl_xor(m, 2));
        m = fmaxf(m, __shfl_xor(m, 4));
        m = fmaxf(m, __shfl_xor(m, 8));
        float p = __expf(a - m);
        float s = p;
        s += __shfl_xor(s, 1);
        s += __shfl_xor(s, 2);
        s += __shfl_xor(s, 4);
        s += __shfl_xor(s, 8);
        gates[(size_t)(b0 + w * 4 + r) * 64 + lane] = p / s;  // [b][t*16+e]
    }
}

// ---------------- Kernel B: expert GEMM + relu + gate contraction ----------------
// Counted-vmcnt double-buffered pipeline; gload_lds; swizzled reads (r16).
#define BM 128
#define BN 256
#define BK 64

__global__ __launch_bounds__(512) void moe_kernel(
        const unsigned short* __restrict__ xb,
        const unsigned short* __restrict__ ekT,
        const float* __restrict__ eb, const float* __restrict__ gates,
        float* __restrict__ out) {
    __shared__ __align__(64) char smem[98304];  // buf0 @0, buf1 @49152; A 16K + B 32K each
    const int tid = threadIdx.x;
    const int wave = tid >> 6, lane = tid & 63;
    const int llo = lane & 15, lhi = lane >> 4;
    const int g = (blockIdx.x & 7) * 128 + (blockIdx.x >> 3);  // XCD swizzle
    const int b0 = (g >> 3) * BM;
    const int n0 = (g & 7) * BN;
    const int mr = (wave >> 2) * 64, nc = (wave & 3) * 64;
    f32x4 acc[4][4] = {};

#define STAGE(buf, kt_) do {                                                   \
    const int k0_ = (kt_) * BK;                                                \
    char* aB_ = smem + (buf) * 49152;                                          \
    char* bB_ = aB_ + 16384;                                                   \
    _Pragma("unroll")                                                          \
    for (int i_ = 0; i_ < 2; ++i_) {                                           \
        const int cb_ = i_ * 512 + wave * 64;                                  \
        const int c_ = cb_ + lane;                                             \
        GLOAD16(xb + (size_t)(b0 + (c_ >> 3)) * Dd + k0_ + (c_ & 7) * 8,       \
                aB_ + cb_ * 16);                                               \
    }                                                                          \
    _Pragma("unroll")                                                          \
    for (int i_ = 0; i_ < 4; ++i_) {                                           \
        const int cb_ = i_ * 512 + wave * 64;                                  \
        const int c_ = cb_ + lane;                                             \
        GLOAD16(ekT + (size_t)(n0 + (c_ >> 3)) * Dd + k0_ + (c_ & 7) * 8,      \
                bB_ + cb_ * 16);                                               \
    }                                                                          \
} while (0)

    STAGE(0, 0);
    STAGE(1, 1);
    for (int kt = 0; kt < Dd / BK; ++kt) {
        const int cur = kt & 1;
        // counted wait: 6 loads of tile kt+1 may stay in flight (never drain
        // to 0 mid-loop). Single asm block = bidirectional code-motion fence.
        if (kt < 7) asm volatile("s_waitcnt vmcnt(6)\ns_barrier" ::: "memory");
        else        asm volatile("s_waitcnt vmcnt(0)\ns_barrier" ::: "memory");
        const char* aB = smem + cur * 49152;
        const char* bB = aB + 16384;
        #pragma unroll
        for (int ks = 0; ks < BK; ks += 32) {
            bf16x8 aF[4], bF[4];
            const int sl = (ks >> 3) + lhi;          // logical 16B slot
            const int ph = (sl ^ (llo & 7)) << 4;    // physical slot (row&7==llo&7)
            #pragma unroll
            for (int mi = 0; mi < 4; ++mi)
                aF[mi] = *(const bf16x8*)(aB + (mr + mi * 16 + llo) * 128 + ph);
            #pragma unroll
            for (int ni = 0; ni < 4; ++ni)
                bF[ni] = *(const bf16x8*)(bB + (nc + ni * 16 + llo) * 128 + ph);
            #pragma unroll
            for (int mi = 0; mi < 4; ++mi)
                #pragma unroll
                for (int ni = 0; ni < 4; ++ni)
                    acc[mi][ni] = __builtin_amdgcn_mfma_f32_16x16x32_bf16(
                        aF[mi], bF[ni], acc[mi][ni], 0, 0, 0);
        }
        asm volatile("s_barrier" ::: "memory");  // all reads of buf[cur] done
        if (kt < 6) STAGE(cur, kt + 2);          // refill retired buffer
    }
    __syncthreads();

    // -------- two-pass epilogue (r16 verbatim): eo half [64][264] @ smem --------
    unsigned short* eoh = (unsigned short*)smem;
    #pragma unroll
    for (int pass = 0; pass < 2; ++pass) {
        __syncthreads();
        if ((mr >> 6) == pass) {
            #pragma unroll
            for (int ni = 0; ni < 4; ++ni) {
                const int col = nc + ni * 16 + llo;
                const float ebv = eb[n0 + col];
                #pragma unroll
                for (int mi = 0; mi < 4; ++mi)
                    #pragma unroll
                    for (int j = 0; j < 4; ++j) {
                        int rl = mi * 16 + lhi * 4 + j;
                        eoh[rl * 264 + col] = f2bf(fmaxf(acc[mi][ni][j] + ebv, 0.f));
                    }
            }
        }
        __syncthreads();
        #pragma unroll
        for (int i = 0; i < 2; ++i) {
            int f = i * 512 + tid;
            int ml = f >> 4, ul = f & 15;
            const unsigned short* er = eoh + ml * 264 + ul * 16;
            const int brow = b0 + pass * 64 + ml;
            const float* gr = gates + (size_t)brow * 64;
            float o0 = 0.f, o1 = 0.f, o2 = 0.f, o3 = 0.f;
            #pragma unroll
            for (int e = 0; e < 16; ++e) {
                float v = bf2f(er[e]);
                o0 = fmaf(v, gr[e], o0);
                o1 = fmaf(v, gr[16 + e], o1);
                o2 = fmaf(v, gr[32 + e], o2);
                o3 = fmaf(v, gr[48 + e], o3);
            }
            size_t base = (size_t)brow * Uu + (n0 >> 4) + ul;
            out[base] = o0;
            out[(size_t)Bsz * Uu + base] = o1;
            out[2 * (size_t)Bsz * Uu + base] = o2;
            out[3 * (size_t)Bsz * Uu + base] = o3;
        }
    }
#undef STAGE
}

extern "C" void kernel_launch(void* const* d_in, const int* in_sizes, int n_in,
                              void* d_out, int out_size, void* d_ws, size_t ws_size,
                              hipStream_t stream) {
    const float* x  = (const float*)d_in[0];
    const float* ek = (const float*)d_in[1];
    const float* eb = (const float*)d_in[2];
    const float* gk = (const float*)d_in[3];
    const float* gb = (const float*)d_in[4];
    float* out = (float*)d_out;

    char* wsb = (char*)d_ws;
    float* gates       = (float*)wsb;                            // 4 MiB @ 0
    unsigned short* xb  = (unsigned short*)(wsb + (4u << 20));   // 16 MiB @ 4
    unsigned short* ekT = (unsigned short*)(wsb + (20u << 20));  // 2 MiB @ 20

    prep_kernel<<<1280, 256, 0, stream>>>(x, gk, gb, ek, gates, xb, ekT);
    moe_kernel<<<1024, 512, 0, stream>>>(xb, ekT, eb, gates, out);
}